// Round 3
// baseline (2801.398 us; speedup 1.0000x reference)
//
#include <hip/hip_runtime.h>

#define N_NODES 25600
#define N_EDGES 409600
#define EPSV 1e-5f

// ---------------- transform layer 1: [N,192] -> prelu(grouped conv) -> y1 [N,192] ----------------
// node n stream s = n&1 selects posture (0) / motion (1) weights.
__global__ __launch_bounds__(256) void t1_kernel(
    const float* __restrict__ h,
    const float* __restrict__ tpw1, const float* __restrict__ tpb1,
    const float* __restrict__ tpa,
    const float* __restrict__ tmw1, const float* __restrict__ tmb1,
    const float* __restrict__ tma,
    float* __restrict__ y1)
{
    const int gid = blockIdx.x * 256 + threadIdx.x;   // over N*192, exact
    const int n = gid / 192, o = gid - n * 192;
    const int s = n & 1;
    const float* w1 = s ? tmw1 : tpw1;
    const float* b1 = s ? tmb1 : tpb1;
    const float alpha = (s ? tma : tpa)[0];
    const int g = o >> 6;                              // group of output channel
    const float* hrow = h + n * 192 + g * 64;
    const float* wrow = w1 + o * 64;
    float acc = b1[o];
    #pragma unroll 8
    for (int i = 0; i < 64; i++)
        acc += wrow[i] * hrow[i];
    y1[gid] = acc >= 0.f ? acc : alpha * acc;
}

// ---------------- transform layer 2: y1 [N,192] -> grouped conv -> x [N,96] ----------------
__global__ __launch_bounds__(256) void t2_kernel(
    const float* __restrict__ y1,
    const float* __restrict__ tpw2, const float* __restrict__ tpb2,
    const float* __restrict__ tmw2, const float* __restrict__ tmb2,
    float* __restrict__ xout)
{
    const int gid = blockIdx.x * 256 + threadIdx.x;   // over N*96, exact
    const int n = gid / 96, o = gid - n * 96;
    const int s = n & 1;
    const float* w2 = s ? tmw2 : tpw2;
    const float* b2 = s ? tmb2 : tpb2;
    const int g = o >> 5;                              // 96 outputs, 3 groups of 32
    const float* inrow = y1 + n * 192 + g * 64;
    const float* wrow = w2 + o * 64;
    float acc = b2[o];
    #pragma unroll 8
    for (int i = 0; i < 64; i++)
        acc += wrow[i] * inrow[i];
    xout[gid] = acc;
}

// ---------------- gate: e = tanh(prelu((x[dst]*x[src]) @ W1 + b1) @ W2 + b2) ----------------
#define GT 32   // edges per block

__global__ __launch_bounds__(256) void gate_kernel(
    const float* __restrict__ xf,
    const int* __restrict__ src, const int* __restrict__ dst,
    const float* __restrict__ gW1, const float* __restrict__ gb1,
    const float* __restrict__ ga,  const float* __restrict__ gW2,
    const float* __restrict__ gb2, int layer,
    float* __restrict__ e_out)
{
    __shared__ float W1s[96 * 96];            // [k][n] (36.9 KB)
    __shared__ float h2s[GT * 96];            // [e][k]
    __shared__ float us[GT * 96];             // [e][n]
    __shared__ float W2s[96];
    __shared__ float b1s[96];
    __shared__ int sE[GT];
    __shared__ int dE[GT];

    const int tid = threadIdx.x;
    const float* W1p = gW1 + layer * 9216;    // [96,96] row-major [k][n]
    for (int idx = tid; idx < 9216; idx += 256) W1s[idx] = W1p[idx];
    if (tid < 96) {
        W2s[tid] = gW2[layer * 96 + tid];
        b1s[tid] = gb1[layer * 96 + tid];
    }
    const float alpha = ga[layer];
    const float b2v = gb2[layer];
    const int base = blockIdx.x * GT;
    if (tid < GT) { sE[tid] = src[base + tid]; dE[tid] = dst[base + tid]; }
    __syncthreads();

    // stage h2 = x[src]*x[dst] (GT x 96)
    #pragma unroll
    for (int r = 0; r < GT * 96 / 256; r++) {
        int u = r * 256 + tid;
        int e = u / 96, i = u - e * 96;
        h2s[u] = xf[sE[e] * 96 + i] * xf[dE[e] * 96 + i];
    }
    __syncthreads();

    // pass A: us[e][n] = prelu(h2[e,:] @ W1[:,n] + b1[n]) * W2[n]
    #pragma unroll
    for (int r = 0; r < GT * 96 / 256; r++) {
        int u = r * 256 + tid;
        int e = u / 96, n = u - e * 96;
        float acc = b1s[n];
        const float* hr = &h2s[e * 96];
        #pragma unroll 8
        for (int k = 0; k < 96; k++)
            acc += hr[k] * W1s[k * 96 + n];
        acc = acc >= 0.f ? acc : alpha * acc;
        us[u] = acc * W2s[n];
    }
    __syncthreads();

    // pass B: per-edge sum over n, tanh, write
    if (tid < GT) {
        float ssum = 0.f;
        #pragma unroll 8
        for (int n = 0; n < 96; n++) ssum += us[tid * 96 + n];
        e_out[base + tid] = tanhf(ssum + b2v);
    }
}

// ---------------- segment_sum(x[src]*e, dst) via atomics ----------------
__global__ __launch_bounds__(256) void aggregate_kernel(
    const float* __restrict__ xf, const int* __restrict__ src,
    const int* __restrict__ dst, const float* __restrict__ ef,
    float* __restrict__ z)
{
    int gid = blockIdx.x * 256 + threadIdx.x;          // over E*96, exact
    int e = gid / 96, i = gid - e * 96;
    float v = xf[src[e] * 96 + i] * ef[e];
    atomicAdd(&z[dst[e] * 96 + i], v);
}

// ---------------- y = prelu(BN(LN(z + x))) ; one block (128 thr) per node ----------------
__global__ __launch_bounds__(128) void norm_kernel(
    const float* __restrict__ z, const float* __restrict__ xin,
    const float* __restrict__ lng, const float* __restrict__ lnb,
    const float* __restrict__ bng, const float* __restrict__ bnb,
    const float* __restrict__ bnrm, const float* __restrict__ bnrv,
    const float* __restrict__ acta, int layer,
    float* __restrict__ xout)
{
    __shared__ float red[128];
    const int n = blockIdx.x;
    const int tid = threadIdx.x;
    float v = 0.f;
    if (tid < 96) v = z[n * 96 + tid] + xin[n * 96 + tid];
    red[tid] = (tid < 96) ? v : 0.f;
    __syncthreads();
    for (int sft = 64; sft > 0; sft >>= 1) {
        if (tid < sft) red[tid] += red[tid + sft];
        __syncthreads();
    }
    const float mean = red[0] * (1.f / 96.f);
    __syncthreads();
    const float d = (tid < 96) ? (v - mean) : 0.f;
    red[tid] = d * d;
    __syncthreads();
    for (int sft = 64; sft > 0; sft >>= 1) {
        if (tid < sft) red[tid] += red[tid + sft];
        __syncthreads();
    }
    const float rstd = rsqrtf(red[0] * (1.f / 96.f) + EPSV);
    if (tid < 96) {
        const int c = layer * 96 + tid;
        float y = d * rstd * lng[c] + lnb[c];
        y = (y - bnrm[c]) * rsqrtf(bnrv[c] + EPSV) * bng[c] + bnb[c];
        const float a = acta[layer];
        xout[n * 96 + tid] = y >= 0.f ? y : a * y;
    }
}

// ---------------- out[n,o] = [x0|x1|x2](n,:) @ t2_w[:,o] + t2_b[o] ----------------
__global__ __launch_bounds__(256) void final_kernel(
    const float* __restrict__ x0, const float* __restrict__ x1, const float* __restrict__ x2,
    const float* __restrict__ t2w, const float* __restrict__ t2b,
    float* __restrict__ out)
{
    const int gid = blockIdx.x * 256 + threadIdx.x;    // over N*128, exact
    const int n = gid >> 7, o = gid & 127;
    float acc = t2b[o];
    #pragma unroll 8
    for (int c = 0; c < 96; c++) acc += x0[n * 96 + c] * t2w[c * 128 + o];
    #pragma unroll 8
    for (int c = 0; c < 96; c++) acc += x1[n * 96 + c] * t2w[(96 + c) * 128 + o];
    #pragma unroll 8
    for (int c = 0; c < 96; c++) acc += x2[n * 96 + c] * t2w[(192 + c) * 128 + o];
    out[gid] = acc;
}

extern "C" void kernel_launch(void* const* d_in, const int* in_sizes, int n_in,
                              void* d_out, int out_size, void* d_ws, size_t ws_size,
                              hipStream_t stream)
{
    const float* h    = (const float*)d_in[0];
    const int*   src  = (const int*)d_in[1];
    const int*   dst  = (const int*)d_in[2];
    const float* tpw1 = (const float*)d_in[3];
    const float* tpb1 = (const float*)d_in[4];
    const float* tpa  = (const float*)d_in[5];
    const float* tpw2 = (const float*)d_in[6];
    const float* tpb2 = (const float*)d_in[7];
    const float* tmw1 = (const float*)d_in[8];
    const float* tmb1 = (const float*)d_in[9];
    const float* tma  = (const float*)d_in[10];
    const float* tmw2 = (const float*)d_in[11];
    const float* tmb2 = (const float*)d_in[12];
    const float* lng  = (const float*)d_in[13];
    const float* lnb  = (const float*)d_in[14];
    const float* bng  = (const float*)d_in[15];
    const float* bnb  = (const float*)d_in[16];
    const float* bnrm = (const float*)d_in[17];
    const float* bnrv = (const float*)d_in[18];
    const float* acta = (const float*)d_in[19];
    const float* gW1  = (const float*)d_in[20];
    const float* gb1  = (const float*)d_in[21];
    const float* ga   = (const float*)d_in[22];
    const float* gW2  = (const float*)d_in[23];
    const float* gb2  = (const float*)d_in[24];
    const float* t2w  = (const float*)d_in[25];
    const float* t2b  = (const float*)d_in[26];

    float* ws = (float*)d_ws;
    float* x0 = ws;                         // N*96
    float* x1 = x0 + N_NODES * 96;          // N*96
    float* x2 = x1 + N_NODES * 96;          // N*96
    float* z  = x2 + N_NODES * 96;          // N*96
    float* eb = z  + N_NODES * 96;          // E
    float* y1 = x1;                         // alias: N*192 spans x1+x2, consumed before x1 written

    float* out = (float*)d_out;             // N*128 fp32
    float* ee  = out + N_NODES * 128;       // 2E fp32

    t1_kernel<<<N_NODES * 192 / 256, 256, 0, stream>>>(h, tpw1, tpb1, tpa, tmw1, tmb1, tma, y1);
    t2_kernel<<<N_NODES * 96 / 256, 256, 0, stream>>>(y1, tpw2, tpb2, tmw2, tmb2, x0);

    // ---- layer 0 ----
    gate_kernel<<<N_EDGES / GT, 256, 0, stream>>>(x0, src, dst, gW1, gb1, ga, gW2, gb2, 0, eb);
    hipMemsetAsync(z, 0, N_NODES * 96 * sizeof(float), stream);
    aggregate_kernel<<<N_EDGES * 96 / 256, 256, 0, stream>>>(x0, src, dst, eb, z);
    norm_kernel<<<N_NODES, 128, 0, stream>>>(z, x0, lng, lnb, bng, bnb, bnrm, bnrv, acta, 0, x1);
    gate_kernel<<<N_EDGES / GT, 256, 0, stream>>>(x1, src, dst, gW1, gb1, ga, gW2, gb2, 0, ee);

    // ---- layer 1 ----
    gate_kernel<<<N_EDGES / GT, 256, 0, stream>>>(x1, src, dst, gW1, gb1, ga, gW2, gb2, 1, eb);
    hipMemsetAsync(z, 0, N_NODES * 96 * sizeof(float), stream);
    aggregate_kernel<<<N_EDGES * 96 / 256, 256, 0, stream>>>(x1, src, dst, eb, z);
    norm_kernel<<<N_NODES, 128, 0, stream>>>(z, x1, lng, lnb, bng, bnb, bnrm, bnrv, acta, 1, x2);
    gate_kernel<<<N_EDGES / GT, 256, 0, stream>>>(x2, src, dst, gW1, gb1, ga, gW2, gb2, 1, ee + N_EDGES);

    // ---- readout ----
    final_kernel<<<N_NODES * 128 / 256, 256, 0, stream>>>(x0, x1, x2, t2w, t2b, out);
}

// Round 4
// 1142.212 us; speedup vs baseline: 2.4526x; 2.4526x over previous
//
#include <hip/hip_runtime.h>

#define N_NODES 25600
#define N_EDGES 409600
#define EPSV 1e-5f

__device__ __forceinline__ unsigned short f2bf(float f) {
    unsigned int x = __float_as_uint(f);
    x += 0x7fffu + ((x >> 16) & 1u);
    return (unsigned short)(x >> 16);
}

// ---------------- transform layer 1: [N,192] -> prelu(grouped conv) -> y1 [N,192] ----------------
__global__ __launch_bounds__(256) void t1_kernel(
    const float* __restrict__ h,
    const float* __restrict__ tpw1, const float* __restrict__ tpb1,
    const float* __restrict__ tpa,
    const float* __restrict__ tmw1, const float* __restrict__ tmb1,
    const float* __restrict__ tma,
    float* __restrict__ y1)
{
    const int gid = blockIdx.x * 256 + threadIdx.x;   // over N*192, exact
    const int n = gid / 192, o = gid - n * 192;
    const int s = n & 1;
    const float* w1 = s ? tmw1 : tpw1;
    const float* b1 = s ? tmb1 : tpb1;
    const float alpha = (s ? tma : tpa)[0];
    const int g = o >> 6;
    const float* hrow = h + n * 192 + g * 64;
    const float* wrow = w1 + o * 64;
    float acc = b1[o];
    #pragma unroll 8
    for (int i = 0; i < 64; i++)
        acc += wrow[i] * hrow[i];
    y1[gid] = acc >= 0.f ? acc : alpha * acc;
}

// ---------------- transform layer 2: y1 [N,192] -> grouped conv -> x [N,96] ----------------
__global__ __launch_bounds__(256) void t2_kernel(
    const float* __restrict__ y1,
    const float* __restrict__ tpw2, const float* __restrict__ tpb2,
    const float* __restrict__ tmw2, const float* __restrict__ tmb2,
    float* __restrict__ xout)
{
    const int gid = blockIdx.x * 256 + threadIdx.x;   // over N*96, exact
    const int n = gid / 96, o = gid - n * 96;
    const int s = n & 1;
    const float* w2 = s ? tmw2 : tpw2;
    const float* b2 = s ? tmb2 : tpb2;
    const int g = o >> 5;
    const float* inrow = y1 + n * 192 + g * 64;
    const float* wrow = w2 + o * 64;
    float acc = b2[o];
    #pragma unroll 8
    for (int i = 0; i < 64; i++)
        acc += wrow[i] * inrow[i];
    xout[gid] = acc;
}

// ---------------- gate (MFMA): e = tanh(prelu((x[dst]*x[src]) @ W1 + b1) @ W2 + b2) ----------------
using frag_ab = __attribute__((ext_vector_type(8))) short;  // 8 bf16 = 4 VGPRs
using frag_cd = __attribute__((ext_vector_type(4))) float;

#define WST 104   // LDS row stride (bf16 elems): 208 B = 16B-aligned, non-pow-2

__global__ __launch_bounds__(256) void gate_kernel(
    const float* __restrict__ xf,
    const int* __restrict__ src, const int* __restrict__ dst,
    const float* __restrict__ gW1, const float* __restrict__ gb1,
    const float* __restrict__ ga,  const float* __restrict__ gW2,
    const float* __restrict__ gb2, int layer,
    float* __restrict__ e_out)
{
    __shared__ alignas(16) unsigned short W1t[96 * WST];  // [n][k] transposed, bf16
    __shared__ alignas(16) unsigned short h2s[64 * WST];  // [edge][k] bf16
    __shared__ float W2s[96];
    __shared__ float b1s[96];
    __shared__ int ssrc[64];
    __shared__ int sdst[64];

    const int tid = threadIdx.x;
    const float* W1p = gW1 + layer * 9216;                // [k][n] row-major in global
    for (int idx = tid; idx < 9216; idx += 256) {
        int k = idx / 96, n = idx - k * 96;
        W1t[n * WST + k] = f2bf(W1p[idx]);
    }
    if (tid < 96) {
        W2s[tid] = gW2[layer * 96 + tid];
        b1s[tid] = gb1[layer * 96 + tid];
    }
    const float alpha = ga[layer];
    const float b2v = gb2[layer];
    __syncthreads();

    const int lane = tid & 63;
    const int wv   = tid >> 6;
    const int quad = lane >> 4;
    const int lcol = lane & 15;
    const int m0   = wv * 16;

    for (int tile = blockIdx.x; tile < N_EDGES / 64; tile += gridDim.x) {
        const int base = tile * 64;
        if (tid < 64) { ssrc[tid] = src[base + tid]; sdst[tid] = dst[base + tid]; }
        __syncthreads();
        // phase 1: h2 = x[src]*x[dst], bf16 into LDS (64 edges x 96 dims)
        #pragma unroll
        for (int r = 0; r < 24; r++) {
            int m = r * 256 + tid;
            int eL = m / 96, i = m - eL * 96;
            float v = xf[ssrc[eL] * 96 + i] * xf[sdst[eL] * 96 + i];
            h2s[eL * WST + i] = f2bf(v);
        }
        __syncthreads();

        // phase 2: u = h2 @ W1 via MFMA. Wave wv owns edge rows m0..m0+15, all 96 outputs.
        // A-frag: A[m=lcol][k=quad*8+j]; B-frag: B[n=lcol][k=quad*8+j] (W1t is [n][k]).
        frag_cd acc[6];
        #pragma unroll
        for (int nt = 0; nt < 6; nt++) acc[nt] = (frag_cd){0.f, 0.f, 0.f, 0.f};
        const int mrow = m0 + lcol;
        #pragma unroll
        for (int kt = 0; kt < 3; kt++) {
            const int k0 = kt * 32 + quad * 8;
            frag_ab afrag = *(const frag_ab*)&h2s[mrow * WST + k0];
            #pragma unroll
            for (int nt = 0; nt < 6; nt++) {
                frag_ab bfrag = *(const frag_ab*)&W1t[(nt * 16 + lcol) * WST + k0];
                acc[nt] = __builtin_amdgcn_mfma_f32_16x16x32_bf16(afrag, bfrag, acc[nt], 0, 0, 0);
            }
        }
        // phase 3: +b1, prelu, dot with W2, tanh.
        // C/D layout: col = lcol (output chan in nt tile), row = quad*4+reg (edge).
        float psum[4] = {0.f, 0.f, 0.f, 0.f};
        #pragma unroll
        for (int nt = 0; nt < 6; nt++) {
            float w2v = W2s[nt * 16 + lcol];
            float b1v = b1s[nt * 16 + lcol];
            #pragma unroll
            for (int reg = 0; reg < 4; reg++) {
                float u = acc[nt][reg] + b1v;
                u = u >= 0.f ? u : alpha * u;
                psum[reg] += u * w2v;
            }
        }
        #pragma unroll
        for (int off = 1; off < 16; off <<= 1) {
            #pragma unroll
            for (int reg = 0; reg < 4; reg++)
                psum[reg] += __shfl_xor(psum[reg], off, 64);
        }
        if (lcol == 0) {
            #pragma unroll
            for (int reg = 0; reg < 4; reg++)
                e_out[base + m0 + quad * 4 + reg] = tanhf(psum[reg] + b2v);
        }
        __syncthreads();
    }
}

// ---------------- segment_sum(x[src]*e, dst) via atomics ----------------
__global__ __launch_bounds__(256) void aggregate_kernel(
    const float* __restrict__ xf, const int* __restrict__ src,
    const int* __restrict__ dst, const float* __restrict__ ef,
    float* __restrict__ z)
{
    int gid = blockIdx.x * 256 + threadIdx.x;          // over E*96, exact
    int e = gid / 96, i = gid - e * 96;
    float v = xf[src[e] * 96 + i] * ef[e];
    atomicAdd(&z[dst[e] * 96 + i], v);
}

// ---------------- y = prelu(BN(LN(z + x))) ; one block (128 thr) per node ----------------
__global__ __launch_bounds__(128) void norm_kernel(
    const float* __restrict__ z, const float* __restrict__ xin,
    const float* __restrict__ lng, const float* __restrict__ lnb,
    const float* __restrict__ bng, const float* __restrict__ bnb,
    const float* __restrict__ bnrm, const float* __restrict__ bnrv,
    const float* __restrict__ acta, int layer,
    float* __restrict__ xout)
{
    __shared__ float red[128];
    const int n = blockIdx.x;
    const int tid = threadIdx.x;
    float v = 0.f;
    if (tid < 96) v = z[n * 96 + tid] + xin[n * 96 + tid];
    red[tid] = (tid < 96) ? v : 0.f;
    __syncthreads();
    for (int sft = 64; sft > 0; sft >>= 1) {
        if (tid < sft) red[tid] += red[tid + sft];
        __syncthreads();
    }
    const float mean = red[0] * (1.f / 96.f);
    __syncthreads();
    const float d = (tid < 96) ? (v - mean) : 0.f;
    red[tid] = d * d;
    __syncthreads();
    for (int sft = 64; sft > 0; sft >>= 1) {
        if (tid < sft) red[tid] += red[tid + sft];
        __syncthreads();
    }
    const float rstd = rsqrtf(red[0] * (1.f / 96.f) + EPSV);
    if (tid < 96) {
        const int c = layer * 96 + tid;
        float y = d * rstd * lng[c] + lnb[c];
        y = (y - bnrm[c]) * rsqrtf(bnrv[c] + EPSV) * bng[c] + bnb[c];
        const float a = acta[layer];
        xout[n * 96 + tid] = y >= 0.f ? y : a * y;
    }
}

// ---------------- out[n,o] = [x0|x1|x2](n,:) @ t2_w[:,o] + t2_b[o] ----------------
__global__ __launch_bounds__(256) void final_kernel(
    const float* __restrict__ x0, const float* __restrict__ x1, const float* __restrict__ x2,
    const float* __restrict__ t2w, const float* __restrict__ t2b,
    float* __restrict__ out)
{
    const int gid = blockIdx.x * 256 + threadIdx.x;    // over N*128, exact
    const int n = gid >> 7, o = gid & 127;
    float acc = t2b[o];
    #pragma unroll 8
    for (int c = 0; c < 96; c++) acc += x0[n * 96 + c] * t2w[c * 128 + o];
    #pragma unroll 8
    for (int c = 0; c < 96; c++) acc += x1[n * 96 + c] * t2w[(96 + c) * 128 + o];
    #pragma unroll 8
    for (int c = 0; c < 96; c++) acc += x2[n * 96 + c] * t2w[(192 + c) * 128 + o];
    out[gid] = acc;
}

extern "C" void kernel_launch(void* const* d_in, const int* in_sizes, int n_in,
                              void* d_out, int out_size, void* d_ws, size_t ws_size,
                              hipStream_t stream)
{
    const float* h    = (const float*)d_in[0];
    const int*   src  = (const int*)d_in[1];
    const int*   dst  = (const int*)d_in[2];
    const float* tpw1 = (const float*)d_in[3];
    const float* tpb1 = (const float*)d_in[4];
    const float* tpa  = (const float*)d_in[5];
    const float* tpw2 = (const float*)d_in[6];
    const float* tpb2 = (const float*)d_in[7];
    const float* tmw1 = (const float*)d_in[8];
    const float* tmb1 = (const float*)d_in[9];
    const float* tma  = (const float*)d_in[10];
    const float* tmw2 = (const float*)d_in[11];
    const float* tmb2 = (const float*)d_in[12];
    const float* lng  = (const float*)d_in[13];
    const float* lnb  = (const float*)d_in[14];
    const float* bng  = (const float*)d_in[15];
    const float* bnb  = (const float*)d_in[16];
    const float* bnrm = (const float*)d_in[17];
    const float* bnrv = (const float*)d_in[18];
    const float* acta = (const float*)d_in[19];
    const float* gW1  = (const float*)d_in[20];
    const float* gb1  = (const float*)d_in[21];
    const float* ga   = (const float*)d_in[22];
    const float* gW2  = (const float*)d_in[23];
    const float* gb2  = (const float*)d_in[24];
    const float* t2w  = (const float*)d_in[25];
    const float* t2b  = (const float*)d_in[26];

    float* ws = (float*)d_ws;
    float* x0 = ws;                         // N*96
    float* x1 = x0 + N_NODES * 96;          // N*96
    float* x2 = x1 + N_NODES * 96;          // N*96
    float* z  = x2 + N_NODES * 96;          // N*96
    float* eb = z  + N_NODES * 96;          // E
    float* y1 = x1;                         // alias: N*192 spans x1+x2, consumed before x1 written

    float* out = (float*)d_out;             // N*128 fp32
    float* ee  = out + N_NODES * 128;       // 2E fp32

    t1_kernel<<<N_NODES * 192 / 256, 256, 0, stream>>>(h, tpw1, tpb1, tpa, tmw1, tmb1, tma, y1);
    t2_kernel<<<N_NODES * 96 / 256, 256, 0, stream>>>(y1, tpw2, tpb2, tmw2, tmb2, x0);

    // ---- layer 0 ----
    gate_kernel<<<1600, 256, 0, stream>>>(x0, src, dst, gW1, gb1, ga, gW2, gb2, 0, eb);
    hipMemsetAsync(z, 0, N_NODES * 96 * sizeof(float), stream);
    aggregate_kernel<<<N_EDGES * 96 / 256, 256, 0, stream>>>(x0, src, dst, eb, z);
    norm_kernel<<<N_NODES, 128, 0, stream>>>(z, x0, lng, lnb, bng, bnb, bnrm, bnrv, acta, 0, x1);
    gate_kernel<<<1600, 256, 0, stream>>>(x1, src, dst, gW1, gb1, ga, gW2, gb2, 0, ee);

    // ---- layer 1 ----
    gate_kernel<<<1600, 256, 0, stream>>>(x1, src, dst, gW1, gb1, ga, gW2, gb2, 1, eb);
    hipMemsetAsync(z, 0, N_NODES * 96 * sizeof(float), stream);
    aggregate_kernel<<<N_EDGES * 96 / 256, 256, 0, stream>>>(x1, src, dst, eb, z);
    norm_kernel<<<N_NODES, 128, 0, stream>>>(z, x1, lng, lnb, bng, bnb, bnrm, bnrv, acta, 1, x2);
    gate_kernel<<<1600, 256, 0, stream>>>(x2, src, dst, gW1, gb1, ga, gW2, gb2, 1, ee + N_EDGES);

    // ---- readout ----
    final_kernel<<<N_NODES * 128 / 256, 256, 0, stream>>>(x0, x1, x2, t2w, t2b, out);
}

// Round 5
// 892.247 us; speedup vs baseline: 3.1397x; 1.2802x over previous
//
#include <hip/hip_runtime.h>

#define N_NODES 25600
#define N_EDGES 409600
#define EPSV 1e-5f

__device__ __forceinline__ unsigned short f2bf(float f) {
    unsigned int x = __float_as_uint(f);
    x += 0x7fffu + ((x >> 16) & 1u);
    return (unsigned short)(x >> 16);
}

using frag_ab = __attribute__((ext_vector_type(8))) short;  // 8 bf16 = 4 VGPRs
using frag_cd = __attribute__((ext_vector_type(4))) float;

#define WST 104   // LDS row stride (bf16 elems): 208 B = 16B-aligned, non-pow-2

// ---------------- transform layer 1: [N,192] -> prelu(grouped conv) -> y1 [N,192] ----------------
__global__ __launch_bounds__(256) void t1_kernel(
    const float* __restrict__ h,
    const float* __restrict__ tpw1, const float* __restrict__ tpb1,
    const float* __restrict__ tpa,
    const float* __restrict__ tmw1, const float* __restrict__ tmb1,
    const float* __restrict__ tma,
    float* __restrict__ y1)
{
    const int gid = blockIdx.x * 256 + threadIdx.x;   // over N*192, exact
    const int n = gid / 192, o = gid - n * 192;
    const int s = n & 1;
    const float* w1 = s ? tmw1 : tpw1;
    const float* b1 = s ? tmb1 : tpb1;
    const float alpha = (s ? tma : tpa)[0];
    const int g = o >> 6;
    const float* hrow = h + n * 192 + g * 64;
    const float* wrow = w1 + o * 64;
    float acc = b1[o];
    #pragma unroll 8
    for (int i = 0; i < 64; i++)
        acc += wrow[i] * hrow[i];
    y1[gid] = acc >= 0.f ? acc : alpha * acc;
}

// ---------------- transform layer 2: y1 [N,192] -> grouped conv -> x [N,96] ----------------
__global__ __launch_bounds__(256) void t2_kernel(
    const float* __restrict__ y1,
    const float* __restrict__ tpw2, const float* __restrict__ tpb2,
    const float* __restrict__ tmw2, const float* __restrict__ tmb2,
    float* __restrict__ xout)
{
    const int gid = blockIdx.x * 256 + threadIdx.x;   // over N*96, exact
    const int n = gid / 96, o = gid - n * 96;
    const int s = n & 1;
    const float* w2 = s ? tmw2 : tpw2;
    const float* b2 = s ? tmb2 : tpb2;
    const int g = o >> 5;
    const float* inrow = y1 + n * 192 + g * 64;
    const float* wrow = w2 + o * 64;
    float acc = b2[o];
    #pragma unroll 8
    for (int i = 0; i < 64; i++)
        acc += wrow[i] * inrow[i];
    xout[gid] = acc;
}

// ---------------- gate (MFMA): e = tanh(prelu((x[dst]*x[src]) @ W1 + b1) @ W2 + b2) ----------------
// DUAL: two weight sets applied to the SAME h2 staging (shared gather) -> two outputs.
template<bool DUAL>
__global__ __launch_bounds__(256) void gate_kernel(
    const float* __restrict__ xf,
    const int* __restrict__ src, const int* __restrict__ dst,
    const float* __restrict__ gW1, const float* __restrict__ gb1,
    const float* __restrict__ ga,  const float* __restrict__ gW2,
    const float* __restrict__ gb2, int layerA, int layerB,
    float* __restrict__ outA, float* __restrict__ outB)
{
    __shared__ alignas(16) unsigned short W1t[(DUAL ? 2 : 1) * 96 * WST]; // [n][k] bf16
    __shared__ alignas(16) unsigned short h2s[64 * WST];                  // [edge][k] bf16
    __shared__ float W2s[(DUAL ? 2 : 1) * 96];
    __shared__ float b1s[(DUAL ? 2 : 1) * 96];
    __shared__ int ssrc[64];
    __shared__ int sdst[64];

    const int tid = threadIdx.x;
    {
        const float* W1p = gW1 + layerA * 9216;           // [k][n] row-major
        for (int idx = tid; idx < 9216; idx += 256) {
            int k = idx / 96, n = idx - k * 96;
            W1t[n * WST + k] = f2bf(W1p[idx]);
        }
        if (DUAL) {
            const float* W1q = gW1 + layerB * 9216;
            for (int idx = tid; idx < 9216; idx += 256) {
                int k = idx / 96, n = idx - k * 96;
                W1t[96 * WST + n * WST + k] = f2bf(W1q[idx]);
            }
        }
    }
    if (tid < 96) {
        W2s[tid] = gW2[layerA * 96 + tid];
        b1s[tid] = gb1[layerA * 96 + tid];
        if (DUAL) {
            W2s[96 + tid] = gW2[layerB * 96 + tid];
            b1s[96 + tid] = gb1[layerB * 96 + tid];
        }
    }
    const float alphaA = ga[layerA];
    const float b2A = gb2[layerA];
    const float alphaB = DUAL ? ga[layerB] : 0.f;
    const float b2B = DUAL ? gb2[layerB] : 0.f;
    __syncthreads();

    const int lane = tid & 63;
    const int wv   = tid >> 6;
    const int quad = lane >> 4;
    const int lcol = lane & 15;
    const int m0   = wv * 16;

    for (int tile = blockIdx.x; tile < N_EDGES / 64; tile += gridDim.x) {
        const int base = tile * 64;
        if (tid < 64) { ssrc[tid] = src[base + tid]; sdst[tid] = dst[base + tid]; }
        __syncthreads();
        // phase 1: h2 = x[src]*x[dst], float4 gather -> 4x bf16 pack -> LDS
        #pragma unroll
        for (int r = 0; r < 6; r++) {
            int m = r * 256 + tid;                   // 0..1535 over (64 edges x 24 quads)
            int eL = m / 24, q = m - eL * 24;
            const float4 a = *(const float4*)&xf[ssrc[eL] * 96 + q * 4];
            const float4 b = *(const float4*)&xf[sdst[eL] * 96 + q * 4];
            unsigned int lo = (unsigned int)f2bf(a.x * b.x) | ((unsigned int)f2bf(a.y * b.y) << 16);
            unsigned int hi = (unsigned int)f2bf(a.z * b.z) | ((unsigned int)f2bf(a.w * b.w) << 16);
            *(uint2*)&h2s[eL * WST + q * 4] = make_uint2(lo, hi);
        }
        __syncthreads();

        // phase 2: u = h2 @ W1 via MFMA (A[m=lcol][k=quad*8+j], B[n=lcol][k=quad*8+j])
        frag_cd accA[6], accB[6];
        #pragma unroll
        for (int nt = 0; nt < 6; nt++) {
            accA[nt] = (frag_cd){0.f, 0.f, 0.f, 0.f};
            if (DUAL) accB[nt] = (frag_cd){0.f, 0.f, 0.f, 0.f};
        }
        const int mrow = m0 + lcol;
        #pragma unroll
        for (int kt = 0; kt < 3; kt++) {
            const int k0 = kt * 32 + quad * 8;
            frag_ab afrag = *(const frag_ab*)&h2s[mrow * WST + k0];
            #pragma unroll
            for (int nt = 0; nt < 6; nt++) {
                frag_ab bfragA = *(const frag_ab*)&W1t[(nt * 16 + lcol) * WST + k0];
                accA[nt] = __builtin_amdgcn_mfma_f32_16x16x32_bf16(afrag, bfragA, accA[nt], 0, 0, 0);
                if (DUAL) {
                    frag_ab bfragB = *(const frag_ab*)&W1t[96 * WST + (nt * 16 + lcol) * WST + k0];
                    accB[nt] = __builtin_amdgcn_mfma_f32_16x16x32_bf16(afrag, bfragB, accB[nt], 0, 0, 0);
                }
            }
        }
        // phase 3: +b1, prelu, dot W2, quad-reduce, tanh.  C/D: col=lcol, row=quad*4+reg.
        float psA[4] = {0.f, 0.f, 0.f, 0.f};
        float psB[4] = {0.f, 0.f, 0.f, 0.f};
        #pragma unroll
        for (int nt = 0; nt < 6; nt++) {
            float w2A = W2s[nt * 16 + lcol];
            float b1A = b1s[nt * 16 + lcol];
            #pragma unroll
            for (int reg = 0; reg < 4; reg++) {
                float u = accA[nt][reg] + b1A;
                u = u >= 0.f ? u : alphaA * u;
                psA[reg] += u * w2A;
            }
            if (DUAL) {
                float w2B = W2s[96 + nt * 16 + lcol];
                float b1B = b1s[96 + nt * 16 + lcol];
                #pragma unroll
                for (int reg = 0; reg < 4; reg++) {
                    float u = accB[nt][reg] + b1B;
                    u = u >= 0.f ? u : alphaB * u;
                    psB[reg] += u * w2B;
                }
            }
        }
        #pragma unroll
        for (int off = 1; off < 16; off <<= 1) {
            #pragma unroll
            for (int reg = 0; reg < 4; reg++) {
                psA[reg] += __shfl_xor(psA[reg], off, 64);
                if (DUAL) psB[reg] += __shfl_xor(psB[reg], off, 64);
            }
        }
        if (lcol == 0) {
            #pragma unroll
            for (int reg = 0; reg < 4; reg++) {
                int er = base + m0 + quad * 4 + reg;
                outA[er] = tanhf(psA[reg] + b2A);
                if (DUAL) outB[er] = tanhf(psB[reg] + b2B);
            }
        }
        __syncthreads();
    }
}

// ---------------- segment_sum(x[src]*e, dst) via atomics ----------------
__global__ __launch_bounds__(256) void aggregate_kernel(
    const float* __restrict__ xf, const int* __restrict__ src,
    const int* __restrict__ dst, const float* __restrict__ ef,
    float* __restrict__ z)
{
    int gid = blockIdx.x * 256 + threadIdx.x;          // over E*96, exact
    int e = gid / 96, i = gid - e * 96;
    float v = xf[src[e] * 96 + i] * ef[e];
    atomicAdd(&z[dst[e] * 96 + i], v);
}

// ---------------- y = prelu(BN(LN(z + x))) ; one block (128 thr) per node ----------------
__global__ __launch_bounds__(128) void norm_kernel(
    const float* __restrict__ z, const float* __restrict__ xin,
    const float* __restrict__ lng, const float* __restrict__ lnb,
    const float* __restrict__ bng, const float* __restrict__ bnb,
    const float* __restrict__ bnrm, const float* __restrict__ bnrv,
    const float* __restrict__ acta, int layer,
    float* __restrict__ xout)
{
    __shared__ float red[128];
    const int n = blockIdx.x;
    const int tid = threadIdx.x;
    float v = 0.f;
    if (tid < 96) v = z[n * 96 + tid] + xin[n * 96 + tid];
    red[tid] = (tid < 96) ? v : 0.f;
    __syncthreads();
    for (int sft = 64; sft > 0; sft >>= 1) {
        if (tid < sft) red[tid] += red[tid + sft];
        __syncthreads();
    }
    const float mean = red[0] * (1.f / 96.f);
    __syncthreads();
    const float d = (tid < 96) ? (v - mean) : 0.f;
    red[tid] = d * d;
    __syncthreads();
    for (int sft = 64; sft > 0; sft >>= 1) {
        if (tid < sft) red[tid] += red[tid + sft];
        __syncthreads();
    }
    const float rstd = rsqrtf(red[0] * (1.f / 96.f) + EPSV);
    if (tid < 96) {
        const int c = layer * 96 + tid;
        float y = d * rstd * lng[c] + lnb[c];
        y = (y - bnrm[c]) * rsqrtf(bnrv[c] + EPSV) * bng[c] + bnb[c];
        const float a = acta[layer];
        xout[n * 96 + tid] = y >= 0.f ? y : a * y;
    }
}

// ---------------- final: out[64-node tile] = hcat @ t2_w + t2_b  (MFMA, K=288 in 3x96) ----------------
__global__ __launch_bounds__(256) void final_mfma(
    const float* __restrict__ x0, const float* __restrict__ x1, const float* __restrict__ x2,
    const float* __restrict__ t2w, const float* __restrict__ t2b,
    float* __restrict__ out)
{
    __shared__ alignas(16) unsigned short As[64 * WST];   // [m][k] bf16, one 96-chunk
    __shared__ alignas(16) unsigned short Bs[128 * WST];  // [n][k] bf16, one 96-chunk

    const int tid  = threadIdx.x;
    const int lane = tid & 63;
    const int wv   = tid >> 6;
    const int quad = lane >> 4;
    const int lcol = lane & 15;
    const int node0 = blockIdx.x * 64;

    frag_cd acc[8];
    #pragma unroll
    for (int nt = 0; nt < 8; nt++) acc[nt] = (frag_cd){0.f, 0.f, 0.f, 0.f};

    for (int ck = 0; ck < 3; ck++) {
        const float* xc = (ck == 0) ? x0 : (ck == 1 ? x1 : x2);
        __syncthreads();
        // stage A chunk: 64 nodes x 96 dims, float4 -> bf16x4
        #pragma unroll
        for (int r = 0; r < 6; r++) {
            int m = r * 256 + tid;                 // 0..1535
            int mm = m / 24, q = m - mm * 24;
            const float4 a = *(const float4*)&xc[(node0 + mm) * 96 + q * 4];
            unsigned int lo = (unsigned int)f2bf(a.x) | ((unsigned int)f2bf(a.y) << 16);
            unsigned int hi = (unsigned int)f2bf(a.z) | ((unsigned int)f2bf(a.w) << 16);
            *(uint2*)&As[mm * WST + q * 4] = make_uint2(lo, hi);
        }
        // stage B chunk transposed: Bs[o][cc] = t2w[(ck*96+cc)*128 + o]
        #pragma unroll
        for (int r = 0; r < 48; r++) {
            int idx = r * 256 + tid;               // 0..12287
            int cc = idx >> 7, o = idx & 127;
            Bs[o * WST + cc] = f2bf(t2w[(ck * 96 + cc) * 128 + o]);
        }
        __syncthreads();
        const int mrow = wv * 16 + lcol;
        #pragma unroll
        for (int kt = 0; kt < 3; kt++) {
            const int k0 = kt * 32 + quad * 8;
            frag_ab afrag = *(const frag_ab*)&As[mrow * WST + k0];
            #pragma unroll
            for (int nt = 0; nt < 8; nt++) {
                frag_ab bfrag = *(const frag_ab*)&Bs[(nt * 16 + lcol) * WST + k0];
                acc[nt] = __builtin_amdgcn_mfma_f32_16x16x32_bf16(afrag, bfrag, acc[nt], 0, 0, 0);
            }
        }
    }
    // epilogue: C/D layout col=lcol, row=quad*4+reg
    const int node = node0 + wv * 16 + quad * 4;
    #pragma unroll
    for (int nt = 0; nt < 8; nt++) {
        const int o = nt * 16 + lcol;
        const float bias = t2b[o];
        #pragma unroll
        for (int reg = 0; reg < 4; reg++)
            out[(node + reg) * 128 + o] = acc[nt][reg] + bias;
    }
}

extern "C" void kernel_launch(void* const* d_in, const int* in_sizes, int n_in,
                              void* d_out, int out_size, void* d_ws, size_t ws_size,
                              hipStream_t stream)
{
    const float* h    = (const float*)d_in[0];
    const int*   src  = (const int*)d_in[1];
    const int*   dst  = (const int*)d_in[2];
    const float* tpw1 = (const float*)d_in[3];
    const float* tpb1 = (const float*)d_in[4];
    const float* tpa  = (const float*)d_in[5];
    const float* tpw2 = (const float*)d_in[6];
    const float* tpb2 = (const float*)d_in[7];
    const float* tmw1 = (const float*)d_in[8];
    const float* tmb1 = (const float*)d_in[9];
    const float* tma  = (const float*)d_in[10];
    const float* tmw2 = (const float*)d_in[11];
    const float* tmb2 = (const float*)d_in[12];
    const float* lng  = (const float*)d_in[13];
    const float* lnb  = (const float*)d_in[14];
    const float* bng  = (const float*)d_in[15];
    const float* bnb  = (const float*)d_in[16];
    const float* bnrm = (const float*)d_in[17];
    const float* bnrv = (const float*)d_in[18];
    const float* acta = (const float*)d_in[19];
    const float* gW1  = (const float*)d_in[20];
    const float* gb1  = (const float*)d_in[21];
    const float* ga   = (const float*)d_in[22];
    const float* gW2  = (const float*)d_in[23];
    const float* gb2  = (const float*)d_in[24];
    const float* t2w  = (const float*)d_in[25];
    const float* t2b  = (const float*)d_in[26];

    float* ws = (float*)d_ws;
    float* x0 = ws;                         // N*96
    float* x1 = x0 + N_NODES * 96;          // N*96
    float* x2 = x1 + N_NODES * 96;          // N*96
    float* z  = x2 + N_NODES * 96;          // N*96
    float* eb = z  + N_NODES * 96;          // E
    float* y1 = x1;                         // alias: N*192 spans x1+x2, consumed before x1 written

    float* out = (float*)d_out;             // N*128 fp32
    float* ee  = out + N_NODES * 128;       // 2E fp32

    t1_kernel<<<N_NODES * 192 / 256, 256, 0, stream>>>(h, tpw1, tpb1, tpa, tmw1, tmb1, tma, y1);
    t2_kernel<<<N_NODES * 96 / 256, 256, 0, stream>>>(y1, tpw2, tpb2, tmw2, tmb2, x0);

    // ---- layer 0 ----
    gate_kernel<false><<<1600, 256, 0, stream>>>(x0, src, dst, gW1, gb1, ga, gW2, gb2, 0, 0, eb, nullptr);
    hipMemsetAsync(z, 0, N_NODES * 96 * sizeof(float), stream);
    aggregate_kernel<<<N_EDGES * 96 / 256, 256, 0, stream>>>(x0, src, dst, eb, z);
    norm_kernel<<<N_NODES, 128, 0, stream>>>(z, x0, lng, lnb, bng, bnb, bnrm, bnrv, acta, 0, x1);

    // ---- fused: es[layer0](x1) -> ee   AND   agg-gate[layer1](x1) -> eb ----
    gate_kernel<true><<<1600, 256, 0, stream>>>(x1, src, dst, gW1, gb1, ga, gW2, gb2, 0, 1, ee, eb);

    // ---- layer 1 ----
    hipMemsetAsync(z, 0, N_NODES * 96 * sizeof(float), stream);
    aggregate_kernel<<<N_EDGES * 96 / 256, 256, 0, stream>>>(x1, src, dst, eb, z);
    norm_kernel<<<N_NODES, 128, 0, stream>>>(z, x1, lng, lnb, bng, bnb, bnrm, bnrv, acta, 1, x2);
    gate_kernel<false><<<1600, 256, 0, stream>>>(x2, src, dst, gW1, gb1, ga, gW2, gb2, 1, 0, ee + N_EDGES, nullptr);

    // ---- readout ----
    final_mfma<<<N_NODES / 64, 256, 0, stream>>>(x0, x1, x2, t2w, t2b, out);
}

// Round 6
// 637.824 us; speedup vs baseline: 4.3921x; 1.3989x over previous
//
#include <hip/hip_runtime.h>

#define N_NODES 25600
#define N_EDGES 409600
#define EPSV 1e-5f

__device__ __forceinline__ unsigned short f2bf(float f) {
    unsigned int x = __float_as_uint(f);
    x += 0x7fffu + ((x >> 16) & 1u);
    return (unsigned short)(x >> 16);
}

using frag_ab = __attribute__((ext_vector_type(8))) short;  // 8 bf16 = 4 VGPRs
using frag_cd = __attribute__((ext_vector_type(4))) float;

#define WST 104   // gate/final LDS row stride (bf16): 208 B, 16B-aligned, non-pow-2
#define TWST 72   // transform weight LDS stride (bf16): 144 B, 16B-aligned, non-pow-2
#define THST 200  // transform h/y1 LDS stride (bf16): 400 B, 16B-aligned, non-pow-2

// ---------------- fused transform: x[n,0:96] = W2g·prelu(W1g·h[n]+b1)+b2, grouped, MFMA ----------------
// Per block: 64 nodes of one stream parity s. w1 [192][64] and w2 [96][64] are already [o][i]
// = MFMA B-frag layout. y1 is repacked IN-PLACE over the consumed hs columns (wave-private rows).
__global__ __launch_bounds__(256) void transform_mfma(
    const float* __restrict__ h,
    const float* __restrict__ tpw1, const float* __restrict__ tpb1, const float* __restrict__ tpa,
    const float* __restrict__ tpw2, const float* __restrict__ tpb2,
    const float* __restrict__ tmw1, const float* __restrict__ tmb1, const float* __restrict__ tma,
    const float* __restrict__ tmw2, const float* __restrict__ tmb2,
    float* __restrict__ xout)
{
    __shared__ alignas(16) unsigned short W1s[192 * TWST]; // [o][i] bf16
    __shared__ alignas(16) unsigned short W2s[96 * TWST];  // [o][i] bf16
    __shared__ alignas(16) unsigned short hs[64 * THST];   // [m][c] bf16; y1 overwrites in place
    __shared__ float b1s[192];
    __shared__ float b2s[96];

    const int tid = threadIdx.x;
    const int s = blockIdx.y;
    const float* w1 = s ? tmw1 : tpw1;
    const float* b1 = s ? tmb1 : tpb1;
    const float* w2 = s ? tmw2 : tpw2;
    const float* b2 = s ? tmb2 : tpb2;
    const float alpha = (s ? tma : tpa)[0];

    // stage weights: float4 loads (contiguous), bf16 pack
    #pragma unroll
    for (int r = 0; r < 12; r++) {
        int idx4 = r * 256 + tid;                    // over 192*16
        int o = idx4 >> 4, i4 = (idx4 & 15) * 4;
        const float4 a = *(const float4*)&w1[o * 64 + i4];
        unsigned int lo = (unsigned int)f2bf(a.x) | ((unsigned int)f2bf(a.y) << 16);
        unsigned int hi = (unsigned int)f2bf(a.z) | ((unsigned int)f2bf(a.w) << 16);
        *(uint2*)&W1s[o * TWST + i4] = make_uint2(lo, hi);
    }
    #pragma unroll
    for (int r = 0; r < 6; r++) {
        int idx4 = r * 256 + tid;                    // over 96*16
        int o = idx4 >> 4, i4 = (idx4 & 15) * 4;
        const float4 a = *(const float4*)&w2[o * 64 + i4];
        unsigned int lo = (unsigned int)f2bf(a.x) | ((unsigned int)f2bf(a.y) << 16);
        unsigned int hi = (unsigned int)f2bf(a.z) | ((unsigned int)f2bf(a.w) << 16);
        *(uint2*)&W2s[o * TWST + i4] = make_uint2(lo, hi);
    }
    if (tid < 192) b1s[tid] = b1[tid];
    if (tid < 96) b2s[tid] = b2[tid];
    __syncthreads();

    const int lane = tid & 63;
    const int wv = tid >> 6;
    const int quad = lane >> 4;
    const int lcol = lane & 15;
    const int m0 = wv * 16;
    const int j0 = blockIdx.x * 64;                  // node-pair base (200 tiles per parity)

    // stage h tile: 64 nodes x 192 dims
    #pragma unroll
    for (int r = 0; r < 12; r++) {
        int idx = r * 256 + tid;                     // over 64*48 float4s
        int m = idx / 48, q = idx - m * 48;
        const float4 a = *(const float4*)&h[(2 * (j0 + m) + s) * 192 + q * 4];
        unsigned int lo = (unsigned int)f2bf(a.x) | ((unsigned int)f2bf(a.y) << 16);
        unsigned int hi = (unsigned int)f2bf(a.z) | ((unsigned int)f2bf(a.w) << 16);
        *(uint2*)&hs[m * THST + q * 4] = make_uint2(lo, hi);
    }
    __syncthreads();

    const int arow = (m0 + lcol) * THST;
    // layer 1: per group g, C[64x64] = hs[:, g*64+k] @ W1s[g*64+o][k]; then prelu -> in-place repack
    #pragma unroll
    for (int g = 0; g < 3; g++) {
        frag_cd acc[4];
        #pragma unroll
        for (int nt = 0; nt < 4; nt++) acc[nt] = (frag_cd){0.f, 0.f, 0.f, 0.f};
        #pragma unroll
        for (int kt = 0; kt < 2; kt++) {
            const int k0 = kt * 32 + quad * 8;
            frag_ab af = *(const frag_ab*)&hs[arow + g * 64 + k0];
            #pragma unroll
            for (int nt = 0; nt < 4; nt++) {
                frag_ab bf = *(const frag_ab*)&W1s[(g * 64 + nt * 16 + lcol) * TWST + k0];
                acc[nt] = __builtin_amdgcn_mfma_f32_16x16x32_bf16(af, bf, acc[nt], 0, 0, 0);
            }
        }
        // epilogue: C/D col=lcol, row=quad*4+reg. Write y1 over consumed hs columns (own rows only).
        #pragma unroll
        for (int nt = 0; nt < 4; nt++) {
            const int o = g * 64 + nt * 16 + lcol;
            const float bv = b1s[o];
            #pragma unroll
            for (int reg = 0; reg < 4; reg++) {
                float u = acc[nt][reg] + bv;
                u = u >= 0.f ? u : alpha * u;
                hs[(m0 + quad * 4 + reg) * THST + o] = f2bf(u);
            }
        }
    }
    // layer 2: per group g2, C[64x32] = y1[:, g2*64+k] @ W2s[g2*32+o][k]  (wave-private rows, no barrier)
    #pragma unroll
    for (int g2 = 0; g2 < 3; g2++) {
        frag_cd acc[2];
        acc[0] = (frag_cd){0.f, 0.f, 0.f, 0.f};
        acc[1] = (frag_cd){0.f, 0.f, 0.f, 0.f};
        #pragma unroll
        for (int kt = 0; kt < 2; kt++) {
            const int k0 = kt * 32 + quad * 8;
            frag_ab af = *(const frag_ab*)&hs[arow + g2 * 64 + k0];
            #pragma unroll
            for (int nt = 0; nt < 2; nt++) {
                frag_ab bf = *(const frag_ab*)&W2s[(g2 * 32 + nt * 16 + lcol) * TWST + k0];
                acc[nt] = __builtin_amdgcn_mfma_f32_16x16x32_bf16(af, bf, acc[nt], 0, 0, 0);
            }
        }
        #pragma unroll
        for (int nt = 0; nt < 2; nt++) {
            const int o2 = g2 * 32 + nt * 16 + lcol;
            const float bv = b2s[o2];
            #pragma unroll
            for (int reg = 0; reg < 4; reg++) {
                const int node = 2 * (j0 + m0 + quad * 4 + reg) + s;
                xout[node * 96 + o2] = acc[nt][reg] + bv;
            }
        }
    }
}

// ---------------- gate (MFMA): e = tanh(prelu((x[dst]*x[src]) @ W1 + b1) @ W2 + b2) ----------------
template<bool DUAL>
__global__ __launch_bounds__(256) void gate_kernel(
    const float* __restrict__ xf,
    const int* __restrict__ src, const int* __restrict__ dst,
    const float* __restrict__ gW1, const float* __restrict__ gb1,
    const float* __restrict__ ga,  const float* __restrict__ gW2,
    const float* __restrict__ gb2, int layerA, int layerB,
    float* __restrict__ outA, float* __restrict__ outB)
{
    __shared__ alignas(16) unsigned short W1t[(DUAL ? 2 : 1) * 96 * WST]; // [n][k] bf16
    __shared__ alignas(16) unsigned short h2s[64 * WST];                  // [edge][k] bf16
    __shared__ float W2s[(DUAL ? 2 : 1) * 96];
    __shared__ float b1s[(DUAL ? 2 : 1) * 96];
    __shared__ int ssrc[64];
    __shared__ int sdst[64];

    const int tid = threadIdx.x;
    {
        const float* W1p = gW1 + layerA * 9216;           // [k][n] row-major
        for (int idx = tid; idx < 9216; idx += 256) {
            int k = idx / 96, n = idx - k * 96;
            W1t[n * WST + k] = f2bf(W1p[idx]);
        }
        if (DUAL) {
            const float* W1q = gW1 + layerB * 9216;
            for (int idx = tid; idx < 9216; idx += 256) {
                int k = idx / 96, n = idx - k * 96;
                W1t[96 * WST + n * WST + k] = f2bf(W1q[idx]);
            }
        }
    }
    if (tid < 96) {
        W2s[tid] = gW2[layerA * 96 + tid];
        b1s[tid] = gb1[layerA * 96 + tid];
        if (DUAL) {
            W2s[96 + tid] = gW2[layerB * 96 + tid];
            b1s[96 + tid] = gb1[layerB * 96 + tid];
        }
    }
    const float alphaA = ga[layerA];
    const float b2A = gb2[layerA];
    const float alphaB = DUAL ? ga[layerB] : 0.f;
    const float b2B = DUAL ? gb2[layerB] : 0.f;
    __syncthreads();

    const int lane = tid & 63;
    const int wv   = tid >> 6;
    const int quad = lane >> 4;
    const int lcol = lane & 15;
    const int m0   = wv * 16;

    for (int tile = blockIdx.x; tile < N_EDGES / 64; tile += gridDim.x) {
        const int base = tile * 64;
        if (tid < 64) { ssrc[tid] = src[base + tid]; sdst[tid] = dst[base + tid]; }
        __syncthreads();
        // phase 1: h2 = x[src]*x[dst], float4 gather -> bf16 pack -> LDS
        #pragma unroll
        for (int r = 0; r < 6; r++) {
            int m = r * 256 + tid;                   // 0..1535 over (64 edges x 24 quads)
            int eL = m / 24, q = m - eL * 24;
            const float4 a = *(const float4*)&xf[ssrc[eL] * 96 + q * 4];
            const float4 b = *(const float4*)&xf[sdst[eL] * 96 + q * 4];
            unsigned int lo = (unsigned int)f2bf(a.x * b.x) | ((unsigned int)f2bf(a.y * b.y) << 16);
            unsigned int hi = (unsigned int)f2bf(a.z * b.z) | ((unsigned int)f2bf(a.w * b.w) << 16);
            *(uint2*)&h2s[eL * WST + q * 4] = make_uint2(lo, hi);
        }
        __syncthreads();

        // phase 2: u = h2 @ W1 via MFMA
        frag_cd accA[6], accB[6];
        #pragma unroll
        for (int nt = 0; nt < 6; nt++) {
            accA[nt] = (frag_cd){0.f, 0.f, 0.f, 0.f};
            if (DUAL) accB[nt] = (frag_cd){0.f, 0.f, 0.f, 0.f};
        }
        const int mrow = m0 + lcol;
        #pragma unroll
        for (int kt = 0; kt < 3; kt++) {
            const int k0 = kt * 32 + quad * 8;
            frag_ab afrag = *(const frag_ab*)&h2s[mrow * WST + k0];
            #pragma unroll
            for (int nt = 0; nt < 6; nt++) {
                frag_ab bfragA = *(const frag_ab*)&W1t[(nt * 16 + lcol) * WST + k0];
                accA[nt] = __builtin_amdgcn_mfma_f32_16x16x32_bf16(afrag, bfragA, accA[nt], 0, 0, 0);
                if (DUAL) {
                    frag_ab bfragB = *(const frag_ab*)&W1t[96 * WST + (nt * 16 + lcol) * WST + k0];
                    accB[nt] = __builtin_amdgcn_mfma_f32_16x16x32_bf16(afrag, bfragB, accB[nt], 0, 0, 0);
                }
            }
        }
        // phase 3: +b1, prelu, dot W2, quad-reduce, tanh.  C/D: col=lcol, row=quad*4+reg.
        float psA[4] = {0.f, 0.f, 0.f, 0.f};
        float psB[4] = {0.f, 0.f, 0.f, 0.f};
        #pragma unroll
        for (int nt = 0; nt < 6; nt++) {
            float w2A = W2s[nt * 16 + lcol];
            float b1A = b1s[nt * 16 + lcol];
            #pragma unroll
            for (int reg = 0; reg < 4; reg++) {
                float u = accA[nt][reg] + b1A;
                u = u >= 0.f ? u : alphaA * u;
                psA[reg] += u * w2A;
            }
            if (DUAL) {
                float w2B = W2s[96 + nt * 16 + lcol];
                float b1B = b1s[96 + nt * 16 + lcol];
                #pragma unroll
                for (int reg = 0; reg < 4; reg++) {
                    float u = accB[nt][reg] + b1B;
                    u = u >= 0.f ? u : alphaB * u;
                    psB[reg] += u * w2B;
                }
            }
        }
        #pragma unroll
        for (int off = 1; off < 16; off <<= 1) {
            #pragma unroll
            for (int reg = 0; reg < 4; reg++) {
                psA[reg] += __shfl_xor(psA[reg], off, 64);
                if (DUAL) psB[reg] += __shfl_xor(psB[reg], off, 64);
            }
        }
        if (lcol == 0) {
            #pragma unroll
            for (int reg = 0; reg < 4; reg++) {
                int er = base + m0 + quad * 4 + reg;
                outA[er] = tanhf(psA[reg] + b2A);
                if (DUAL) outB[er] = tanhf(psB[reg] + b2B);
            }
        }
        __syncthreads();
    }
}

// ---------------- segment_sum(x[src]*e, dst) via atomics ----------------
__global__ __launch_bounds__(256) void aggregate_kernel(
    const float* __restrict__ xf, const int* __restrict__ src,
    const int* __restrict__ dst, const float* __restrict__ ef,
    float* __restrict__ z)
{
    int gid = blockIdx.x * 256 + threadIdx.x;          // over E*96, exact
    int e = gid / 96, i = gid - e * 96;
    float v = xf[src[e] * 96 + i] * ef[e];
    atomicAdd(&z[dst[e] * 96 + i], v);
}

// ---------------- y = prelu(BN(LN(z + x))) ; one block (128 thr) per node ----------------
__global__ __launch_bounds__(128) void norm_kernel(
    const float* __restrict__ z, const float* __restrict__ xin,
    const float* __restrict__ lng, const float* __restrict__ lnb,
    const float* __restrict__ bng, const float* __restrict__ bnb,
    const float* __restrict__ bnrm, const float* __restrict__ bnrv,
    const float* __restrict__ acta, int layer,
    float* __restrict__ xout)
{
    __shared__ float red[128];
    const int n = blockIdx.x;
    const int tid = threadIdx.x;
    float v = 0.f;
    if (tid < 96) v = z[n * 96 + tid] + xin[n * 96 + tid];
    red[tid] = (tid < 96) ? v : 0.f;
    __syncthreads();
    for (int sft = 64; sft > 0; sft >>= 1) {
        if (tid < sft) red[tid] += red[tid + sft];
        __syncthreads();
    }
    const float mean = red[0] * (1.f / 96.f);
    __syncthreads();
    const float d = (tid < 96) ? (v - mean) : 0.f;
    red[tid] = d * d;
    __syncthreads();
    for (int sft = 64; sft > 0; sft >>= 1) {
        if (tid < sft) red[tid] += red[tid + sft];
        __syncthreads();
    }
    const float rstd = rsqrtf(red[0] * (1.f / 96.f) + EPSV);
    if (tid < 96) {
        const int c = layer * 96 + tid;
        float y = d * rstd * lng[c] + lnb[c];
        y = (y - bnrm[c]) * rsqrtf(bnrv[c] + EPSV) * bng[c] + bnb[c];
        const float a = acta[layer];
        xout[n * 96 + tid] = y >= 0.f ? y : a * y;
    }
}

// ---------------- final: out[64-node tile] = hcat @ t2_w + t2_b  (MFMA, K=288 in 3x96) ----------------
__global__ __launch_bounds__(256) void final_mfma(
    const float* __restrict__ x0, const float* __restrict__ x1, const float* __restrict__ x2,
    const float* __restrict__ t2w, const float* __restrict__ t2b,
    float* __restrict__ out)
{
    __shared__ alignas(16) unsigned short As[64 * WST];   // [m][k] bf16, one 96-chunk
    __shared__ alignas(16) unsigned short Bs[128 * WST];  // [n][k] bf16, one 96-chunk

    const int tid  = threadIdx.x;
    const int lane = tid & 63;
    const int wv   = tid >> 6;
    const int quad = lane >> 4;
    const int lcol = lane & 15;
    const int node0 = blockIdx.x * 64;

    frag_cd acc[8];
    #pragma unroll
    for (int nt = 0; nt < 8; nt++) acc[nt] = (frag_cd){0.f, 0.f, 0.f, 0.f};

    for (int ck = 0; ck < 3; ck++) {
        const float* xc = (ck == 0) ? x0 : (ck == 1 ? x1 : x2);
        __syncthreads();
        #pragma unroll
        for (int r = 0; r < 6; r++) {
            int m = r * 256 + tid;                 // 0..1535
            int mm = m / 24, q = m - mm * 24;
            const float4 a = *(const float4*)&xc[(node0 + mm) * 96 + q * 4];
            unsigned int lo = (unsigned int)f2bf(a.x) | ((unsigned int)f2bf(a.y) << 16);
            unsigned int hi = (unsigned int)f2bf(a.z) | ((unsigned int)f2bf(a.w) << 16);
            *(uint2*)&As[mm * WST + q * 4] = make_uint2(lo, hi);
        }
        #pragma unroll
        for (int r = 0; r < 48; r++) {
            int idx = r * 256 + tid;               // 0..12287
            int cc = idx >> 7, o = idx & 127;
            Bs[o * WST + cc] = f2bf(t2w[(ck * 96 + cc) * 128 + o]);
        }
        __syncthreads();
        const int mrow = wv * 16 + lcol;
        #pragma unroll
        for (int kt = 0; kt < 3; kt++) {
            const int k0 = kt * 32 + quad * 8;
            frag_ab afrag = *(const frag_ab*)&As[mrow * WST + k0];
            #pragma unroll
            for (int nt = 0; nt < 8; nt++) {
                frag_ab bfrag = *(const frag_ab*)&Bs[(nt * 16 + lcol) * WST + k0];
                acc[nt] = __builtin_amdgcn_mfma_f32_16x16x32_bf16(afrag, bfrag, acc[nt], 0, 0, 0);
            }
        }
    }
    const int node = node0 + wv * 16 + quad * 4;
    #pragma unroll
    for (int nt = 0; nt < 8; nt++) {
        const int o = nt * 16 + lcol;
        const float bias = t2b[o];
        #pragma unroll
        for (int reg = 0; reg < 4; reg++)
            out[(node + reg) * 128 + o] = acc[nt][reg] + bias;
    }
}

extern "C" void kernel_launch(void* const* d_in, const int* in_sizes, int n_in,
                              void* d_out, int out_size, void* d_ws, size_t ws_size,
                              hipStream_t stream)
{
    const float* h    = (const float*)d_in[0];
    const int*   src  = (const int*)d_in[1];
    const int*   dst  = (const int*)d_in[2];
    const float* tpw1 = (const float*)d_in[3];
    const float* tpb1 = (const float*)d_in[4];
    const float* tpa  = (const float*)d_in[5];
    const float* tpw2 = (const float*)d_in[6];
    const float* tpb2 = (const float*)d_in[7];
    const float* tmw1 = (const float*)d_in[8];
    const float* tmb1 = (const float*)d_in[9];
    const float* tma  = (const float*)d_in[10];
    const float* tmw2 = (const float*)d_in[11];
    const float* tmb2 = (const float*)d_in[12];
    const float* lng  = (const float*)d_in[13];
    const float* lnb  = (const float*)d_in[14];
    const float* bng  = (const float*)d_in[15];
    const float* bnb  = (const float*)d_in[16];
    const float* bnrm = (const float*)d_in[17];
    const float* bnrv = (const float*)d_in[18];
    const float* acta = (const float*)d_in[19];
    const float* gW1  = (const float*)d_in[20];
    const float* gb1  = (const float*)d_in[21];
    const float* ga   = (const float*)d_in[22];
    const float* gW2  = (const float*)d_in[23];
    const float* gb2  = (const float*)d_in[24];
    const float* t2w  = (const float*)d_in[25];
    const float* t2b  = (const float*)d_in[26];

    float* ws = (float*)d_ws;
    float* x0 = ws;                         // N*96
    float* x1 = x0 + N_NODES * 96;          // N*96
    float* x2 = x1 + N_NODES * 96;          // N*96
    float* z  = x2 + N_NODES * 96;          // N*96
    float* eb = z  + N_NODES * 96;          // E

    float* out = (float*)d_out;             // N*128 fp32
    float* ee  = out + N_NODES * 128;       // 2E fp32

    // fused transform (t1+t2): 200 node-tiles per parity
    transform_mfma<<<dim3(200, 2), 256, 0, stream>>>(
        h, tpw1, tpb1, tpa, tpw2, tpb2, tmw1, tmb1, tma, tmw2, tmb2, x0);

    // ---- layer 0 ----
    gate_kernel<false><<<1600, 256, 0, stream>>>(x0, src, dst, gW1, gb1, ga, gW2, gb2, 0, 0, eb, nullptr);
    hipMemsetAsync(z, 0, N_NODES * 96 * sizeof(float), stream);
    aggregate_kernel<<<N_EDGES * 96 / 256, 256, 0, stream>>>(x0, src, dst, eb, z);
    norm_kernel<<<N_NODES, 128, 0, stream>>>(z, x0, lng, lnb, bng, bnb, bnrm, bnrv, acta, 0, x1);

    // ---- fused: es[layer0](x1) -> ee   AND   agg-gate[layer1](x1) -> eb ----
    gate_kernel<true><<<1600, 256, 0, stream>>>(x1, src, dst, gW1, gb1, ga, gW2, gb2, 0, 1, ee, eb);

    // ---- layer 1 ----
    hipMemsetAsync(z, 0, N_NODES * 96 * sizeof(float), stream);
    aggregate_kernel<<<N_EDGES * 96 / 256, 256, 0, stream>>>(x1, src, dst, eb, z);
    norm_kernel<<<N_NODES, 128, 0, stream>>>(z, x1, lng, lnb, bng, bnb, bnrm, bnrv, acta, 1, x2);
    gate_kernel<false><<<1600, 256, 0, stream>>>(x2, src, dst, gW1, gb1, ga, gW2, gb2, 1, 0, ee + N_EDGES, nullptr);

    // ---- readout ----
    final_mfma<<<N_NODES / 64, 256, 0, stream>>>(x0, x1, x2, t2w, t2b, out);
}

// Round 7
// 564.119 us; speedup vs baseline: 4.9660x; 1.1307x over previous
//
#include <hip/hip_runtime.h>

#define N_NODES 25600
#define N_EDGES 409600
#define EPSV 1e-5f

__device__ __forceinline__ unsigned short f2bf(float f) {
    unsigned int x = __float_as_uint(f);
    x += 0x7fffu + ((x >> 16) & 1u);
    return (unsigned short)(x >> 16);
}

using frag_ab = __attribute__((ext_vector_type(8))) short;  // 8 bf16 = 4 VGPRs
using frag_cd = __attribute__((ext_vector_type(4))) float;

#define WST 104   // gate/final LDS row stride (bf16): 208 B, 16B-aligned, non-pow-2
#define TWST 72   // transform weight LDS stride (bf16)
#define THST 200  // transform h/y1 LDS stride (bf16)

// ---------------- fused transform: x[n,0:96] = W2g·prelu(W1g·h[n]+b1)+b2, grouped, MFMA ----------------
__global__ __launch_bounds__(256) void transform_mfma(
    const float* __restrict__ h,
    const float* __restrict__ tpw1, const float* __restrict__ tpb1, const float* __restrict__ tpa,
    const float* __restrict__ tpw2, const float* __restrict__ tpb2,
    const float* __restrict__ tmw1, const float* __restrict__ tmb1, const float* __restrict__ tma,
    const float* __restrict__ tmw2, const float* __restrict__ tmb2,
    float* __restrict__ xout)
{
    __shared__ alignas(16) unsigned short W1s[192 * TWST]; // [o][i] bf16
    __shared__ alignas(16) unsigned short W2s[96 * TWST];  // [o][i] bf16
    __shared__ alignas(16) unsigned short hs[64 * THST];   // [m][c] bf16; y1 overwrites in place
    __shared__ float b1s[192];
    __shared__ float b2s[96];

    const int tid = threadIdx.x;
    const int s = blockIdx.y;
    const float* w1 = s ? tmw1 : tpw1;
    const float* b1 = s ? tmb1 : tpb1;
    const float* w2 = s ? tmw2 : tpw2;
    const float* b2 = s ? tmb2 : tpb2;
    const float alpha = (s ? tma : tpa)[0];

    #pragma unroll
    for (int r = 0; r < 12; r++) {
        int idx4 = r * 256 + tid;                    // over 192*16
        int o = idx4 >> 4, i4 = (idx4 & 15) * 4;
        const float4 a = *(const float4*)&w1[o * 64 + i4];
        unsigned int lo = (unsigned int)f2bf(a.x) | ((unsigned int)f2bf(a.y) << 16);
        unsigned int hi = (unsigned int)f2bf(a.z) | ((unsigned int)f2bf(a.w) << 16);
        *(uint2*)&W1s[o * TWST + i4] = make_uint2(lo, hi);
    }
    #pragma unroll
    for (int r = 0; r < 6; r++) {
        int idx4 = r * 256 + tid;                    // over 96*16
        int o = idx4 >> 4, i4 = (idx4 & 15) * 4;
        const float4 a = *(const float4*)&w2[o * 64 + i4];
        unsigned int lo = (unsigned int)f2bf(a.x) | ((unsigned int)f2bf(a.y) << 16);
        unsigned int hi = (unsigned int)f2bf(a.z) | ((unsigned int)f2bf(a.w) << 16);
        *(uint2*)&W2s[o * TWST + i4] = make_uint2(lo, hi);
    }
    if (tid < 192) b1s[tid] = b1[tid];
    if (tid < 96) b2s[tid] = b2[tid];
    __syncthreads();

    const int lane = tid & 63;
    const int wv = tid >> 6;
    const int quad = lane >> 4;
    const int lcol = lane & 15;
    const int m0 = wv * 16;
    const int j0 = blockIdx.x * 64;

    #pragma unroll
    for (int r = 0; r < 12; r++) {
        int idx = r * 256 + tid;                     // over 64*48 float4s
        int m = idx / 48, q = idx - m * 48;
        const float4 a = *(const float4*)&h[(2 * (j0 + m) + s) * 192 + q * 4];
        unsigned int lo = (unsigned int)f2bf(a.x) | ((unsigned int)f2bf(a.y) << 16);
        unsigned int hi = (unsigned int)f2bf(a.z) | ((unsigned int)f2bf(a.w) << 16);
        *(uint2*)&hs[m * THST + q * 4] = make_uint2(lo, hi);
    }
    __syncthreads();

    const int arow = (m0 + lcol) * THST;
    #pragma unroll
    for (int g = 0; g < 3; g++) {
        frag_cd acc[4];
        #pragma unroll
        for (int nt = 0; nt < 4; nt++) acc[nt] = (frag_cd){0.f, 0.f, 0.f, 0.f};
        #pragma unroll
        for (int kt = 0; kt < 2; kt++) {
            const int k0 = kt * 32 + quad * 8;
            frag_ab af = *(const frag_ab*)&hs[arow + g * 64 + k0];
            #pragma unroll
            for (int nt = 0; nt < 4; nt++) {
                frag_ab bf = *(const frag_ab*)&W1s[(g * 64 + nt * 16 + lcol) * TWST + k0];
                acc[nt] = __builtin_amdgcn_mfma_f32_16x16x32_bf16(af, bf, acc[nt], 0, 0, 0);
            }
        }
        #pragma unroll
        for (int nt = 0; nt < 4; nt++) {
            const int o = g * 64 + nt * 16 + lcol;
            const float bv = b1s[o];
            #pragma unroll
            for (int reg = 0; reg < 4; reg++) {
                float u = acc[nt][reg] + bv;
                u = u >= 0.f ? u : alpha * u;
                hs[(m0 + quad * 4 + reg) * THST + o] = f2bf(u);
            }
        }
    }
    #pragma unroll
    for (int g2 = 0; g2 < 3; g2++) {
        frag_cd acc[2];
        acc[0] = (frag_cd){0.f, 0.f, 0.f, 0.f};
        acc[1] = (frag_cd){0.f, 0.f, 0.f, 0.f};
        #pragma unroll
        for (int kt = 0; kt < 2; kt++) {
            const int k0 = kt * 32 + quad * 8;
            frag_ab af = *(const frag_ab*)&hs[arow + g2 * 64 + k0];
            #pragma unroll
            for (int nt = 0; nt < 2; nt++) {
                frag_ab bf = *(const frag_ab*)&W2s[(g2 * 32 + nt * 16 + lcol) * TWST + k0];
                acc[nt] = __builtin_amdgcn_mfma_f32_16x16x32_bf16(af, bf, acc[nt], 0, 0, 0);
            }
        }
        #pragma unroll
        for (int nt = 0; nt < 2; nt++) {
            const int o2 = g2 * 32 + nt * 16 + lcol;
            const float bv = b2s[o2];
            #pragma unroll
            for (int reg = 0; reg < 4; reg++) {
                const int node = 2 * (j0 + m0 + quad * 4 + reg) + s;
                xout[node * 96 + o2] = acc[nt][reg] + bv;
            }
        }
    }
}

// ---------------- gate (MFMA): e = tanh(prelu((x[dst]*x[src]) @ W1 + b1) @ W2 + b2) ----------------
template<bool DUAL>
__global__ __launch_bounds__(256) void gate_kernel(
    const float* __restrict__ xf,
    const int* __restrict__ src, const int* __restrict__ dst,
    const float* __restrict__ gW1, const float* __restrict__ gb1,
    const float* __restrict__ ga,  const float* __restrict__ gW2,
    const float* __restrict__ gb2, int layerA, int layerB,
    float* __restrict__ outA, float* __restrict__ outB)
{
    __shared__ alignas(16) unsigned short W1t[(DUAL ? 2 : 1) * 96 * WST]; // [n][k] bf16
    __shared__ alignas(16) unsigned short h2s[64 * WST];                  // [edge][k] bf16
    __shared__ float W2s[(DUAL ? 2 : 1) * 96];
    __shared__ float b1s[(DUAL ? 2 : 1) * 96];
    __shared__ int ssrc[64];
    __shared__ int sdst[64];

    const int tid = threadIdx.x;
    {
        const float* W1p = gW1 + layerA * 9216;
        for (int idx = tid; idx < 9216; idx += 256) {
            int k = idx / 96, n = idx - k * 96;
            W1t[n * WST + k] = f2bf(W1p[idx]);
        }
        if (DUAL) {
            const float* W1q = gW1 + layerB * 9216;
            for (int idx = tid; idx < 9216; idx += 256) {
                int k = idx / 96, n = idx - k * 96;
                W1t[96 * WST + n * WST + k] = f2bf(W1q[idx]);
            }
        }
    }
    if (tid < 96) {
        W2s[tid] = gW2[layerA * 96 + tid];
        b1s[tid] = gb1[layerA * 96 + tid];
        if (DUAL) {
            W2s[96 + tid] = gW2[layerB * 96 + tid];
            b1s[96 + tid] = gb1[layerB * 96 + tid];
        }
    }
    const float alphaA = ga[layerA];
    const float b2A = gb2[layerA];
    const float alphaB = DUAL ? ga[layerB] : 0.f;
    const float b2B = DUAL ? gb2[layerB] : 0.f;
    __syncthreads();

    const int lane = tid & 63;
    const int wv   = tid >> 6;
    const int quad = lane >> 4;
    const int lcol = lane & 15;
    const int m0   = wv * 16;

    for (int tile = blockIdx.x; tile < N_EDGES / 64; tile += gridDim.x) {
        const int base = tile * 64;
        if (tid < 64) { ssrc[tid] = src[base + tid]; sdst[tid] = dst[base + tid]; }
        __syncthreads();
        #pragma unroll
        for (int r = 0; r < 6; r++) {
            int m = r * 256 + tid;
            int eL = m / 24, q = m - eL * 24;
            const float4 a = *(const float4*)&xf[ssrc[eL] * 96 + q * 4];
            const float4 b = *(const float4*)&xf[sdst[eL] * 96 + q * 4];
            unsigned int lo = (unsigned int)f2bf(a.x * b.x) | ((unsigned int)f2bf(a.y * b.y) << 16);
            unsigned int hi = (unsigned int)f2bf(a.z * b.z) | ((unsigned int)f2bf(a.w * b.w) << 16);
            *(uint2*)&h2s[eL * WST + q * 4] = make_uint2(lo, hi);
        }
        __syncthreads();

        frag_cd accA[6], accB[6];
        #pragma unroll
        for (int nt = 0; nt < 6; nt++) {
            accA[nt] = (frag_cd){0.f, 0.f, 0.f, 0.f};
            if (DUAL) accB[nt] = (frag_cd){0.f, 0.f, 0.f, 0.f};
        }
        const int mrow = m0 + lcol;
        #pragma unroll
        for (int kt = 0; kt < 3; kt++) {
            const int k0 = kt * 32 + quad * 8;
            frag_ab afrag = *(const frag_ab*)&h2s[mrow * WST + k0];
            #pragma unroll
            for (int nt = 0; nt < 6; nt++) {
                frag_ab bfragA = *(const frag_ab*)&W1t[(nt * 16 + lcol) * WST + k0];
                accA[nt] = __builtin_amdgcn_mfma_f32_16x16x32_bf16(afrag, bfragA, accA[nt], 0, 0, 0);
                if (DUAL) {
                    frag_ab bfragB = *(const frag_ab*)&W1t[96 * WST + (nt * 16 + lcol) * WST + k0];
                    accB[nt] = __builtin_amdgcn_mfma_f32_16x16x32_bf16(afrag, bfragB, accB[nt], 0, 0, 0);
                }
            }
        }
        float psA[4] = {0.f, 0.f, 0.f, 0.f};
        float psB[4] = {0.f, 0.f, 0.f, 0.f};
        #pragma unroll
        for (int nt = 0; nt < 6; nt++) {
            float w2A = W2s[nt * 16 + lcol];
            float b1A = b1s[nt * 16 + lcol];
            #pragma unroll
            for (int reg = 0; reg < 4; reg++) {
                float u = accA[nt][reg] + b1A;
                u = u >= 0.f ? u : alphaA * u;
                psA[reg] += u * w2A;
            }
            if (DUAL) {
                float w2B = W2s[96 + nt * 16 + lcol];
                float b1B = b1s[96 + nt * 16 + lcol];
                #pragma unroll
                for (int reg = 0; reg < 4; reg++) {
                    float u = accB[nt][reg] + b1B;
                    u = u >= 0.f ? u : alphaB * u;
                    psB[reg] += u * w2B;
                }
            }
        }
        #pragma unroll
        for (int off = 1; off < 16; off <<= 1) {
            #pragma unroll
            for (int reg = 0; reg < 4; reg++) {
                psA[reg] += __shfl_xor(psA[reg], off, 64);
                if (DUAL) psB[reg] += __shfl_xor(psB[reg], off, 64);
            }
        }
        if (lcol == 0) {
            #pragma unroll
            for (int reg = 0; reg < 4; reg++) {
                int er = base + m0 + quad * 4 + reg;
                outA[er] = tanhf(psA[reg] + b2A);
                if (DUAL) outB[er] = tanhf(psB[reg] + b2B);
            }
        }
        __syncthreads();
    }
}

// ---------------- CSR build: count / scan / scatter ----------------
__global__ __launch_bounds__(256) void count_kernel(
    const int* __restrict__ dst, int* __restrict__ cnt)
{
    int e = blockIdx.x * 256 + threadIdx.x;          // over E, exact
    atomicAdd(&cnt[dst[e]], 1);
}

// single block, 1024 threads; 25600 = 1024 * 25
__global__ __launch_bounds__(1024) void scan_kernel(
    const int* __restrict__ cnt, int* __restrict__ off, int* __restrict__ cur)
{
    __shared__ int part[1024];
    const int tid = threadIdx.x;
    const int base = tid * 25;
    int loc[25];
    int s = 0;
    #pragma unroll
    for (int i = 0; i < 25; i++) { loc[i] = s; s += cnt[base + i]; }
    part[tid] = s;
    __syncthreads();
    // Hillis-Steele inclusive scan over the 1024 chunk sums
    for (int d = 1; d < 1024; d <<= 1) {
        int t = (tid >= d) ? part[tid - d] : 0;
        __syncthreads();
        part[tid] += t;
        __syncthreads();
    }
    const int basesum = part[tid] - s;               // exclusive base for this chunk
    #pragma unroll
    for (int i = 0; i < 25; i++) {
        int o = basesum + loc[i];
        off[base + i] = o;
        cur[base + i] = o;
    }
    if (tid == 1023) off[N_NODES] = part[1023];      // == E
}

__global__ __launch_bounds__(256) void scatter_kernel(
    const int* __restrict__ dst, int* __restrict__ cur, int* __restrict__ perm)
{
    int e = blockIdx.x * 256 + threadIdx.x;          // over E, exact
    int p = atomicAdd(&cur[dst[e]], 1);
    perm[p] = e;
}

// ---------------- fused: z = segsum(x[src]*e, dst) ; x_next = prelu(BN(LN(z + xin))) ----------------
__global__ __launch_bounds__(128) void agg_norm_kernel(
    const float* __restrict__ xf, const int* __restrict__ srcg,
    const float* __restrict__ ef,
    const int* __restrict__ off, const int* __restrict__ perm,
    const float* __restrict__ xin,
    const float* __restrict__ lng, const float* __restrict__ lnb,
    const float* __restrict__ bng, const float* __restrict__ bnb,
    const float* __restrict__ bnrm, const float* __restrict__ bnrv,
    const float* __restrict__ acta, int layer,
    float* __restrict__ xout)
{
    __shared__ float red[128];
    const int n = blockIdx.x;
    const int tid = threadIdx.x;
    const int beg = off[n], end = off[n + 1];
    float v = 0.f;
    if (tid < 96) {
        for (int j = beg; j < end; j++) {
            const int e = perm[j];
            v += xf[srcg[e] * 96 + tid] * ef[e];
        }
        v += xin[n * 96 + tid];
    }
    red[tid] = (tid < 96) ? v : 0.f;
    __syncthreads();
    for (int sft = 64; sft > 0; sft >>= 1) {
        if (tid < sft) red[tid] += red[tid + sft];
        __syncthreads();
    }
    const float mean = red[0] * (1.f / 96.f);
    __syncthreads();
    const float d = (tid < 96) ? (v - mean) : 0.f;
    red[tid] = d * d;
    __syncthreads();
    for (int sft = 64; sft > 0; sft >>= 1) {
        if (tid < sft) red[tid] += red[tid + sft];
        __syncthreads();
    }
    const float rstd = rsqrtf(red[0] * (1.f / 96.f) + EPSV);
    if (tid < 96) {
        const int c = layer * 96 + tid;
        float y = d * rstd * lng[c] + lnb[c];
        y = (y - bnrm[c]) * rsqrtf(bnrv[c] + EPSV) * bng[c] + bnb[c];
        const float a = acta[layer];
        xout[n * 96 + tid] = y >= 0.f ? y : a * y;
    }
}

// ---------------- final: out[64-node tile] = hcat @ t2_w + t2_b  (MFMA, K=288 in 3x96) ----------------
__global__ __launch_bounds__(256) void final_mfma(
    const float* __restrict__ x0, const float* __restrict__ x1, const float* __restrict__ x2,
    const float* __restrict__ t2w, const float* __restrict__ t2b,
    float* __restrict__ out)
{
    __shared__ alignas(16) unsigned short As[64 * WST];
    __shared__ alignas(16) unsigned short Bs[128 * WST];

    const int tid  = threadIdx.x;
    const int lane = tid & 63;
    const int wv   = tid >> 6;
    const int quad = lane >> 4;
    const int lcol = lane & 15;
    const int node0 = blockIdx.x * 64;

    frag_cd acc[8];
    #pragma unroll
    for (int nt = 0; nt < 8; nt++) acc[nt] = (frag_cd){0.f, 0.f, 0.f, 0.f};

    for (int ck = 0; ck < 3; ck++) {
        const float* xc = (ck == 0) ? x0 : (ck == 1 ? x1 : x2);
        __syncthreads();
        #pragma unroll
        for (int r = 0; r < 6; r++) {
            int m = r * 256 + tid;
            int mm = m / 24, q = m - mm * 24;
            const float4 a = *(const float4*)&xc[(node0 + mm) * 96 + q * 4];
            unsigned int lo = (unsigned int)f2bf(a.x) | ((unsigned int)f2bf(a.y) << 16);
            unsigned int hi = (unsigned int)f2bf(a.z) | ((unsigned int)f2bf(a.w) << 16);
            *(uint2*)&As[mm * WST + q * 4] = make_uint2(lo, hi);
        }
        #pragma unroll
        for (int r = 0; r < 48; r++) {
            int idx = r * 256 + tid;
            int cc = idx >> 7, o = idx & 127;
            Bs[o * WST + cc] = f2bf(t2w[(ck * 96 + cc) * 128 + o]);
        }
        __syncthreads();
        const int mrow = wv * 16 + lcol;
        #pragma unroll
        for (int kt = 0; kt < 3; kt++) {
            const int k0 = kt * 32 + quad * 8;
            frag_ab afrag = *(const frag_ab*)&As[mrow * WST + k0];
            #pragma unroll
            for (int nt = 0; nt < 8; nt++) {
                frag_ab bfrag = *(const frag_ab*)&Bs[(nt * 16 + lcol) * WST + k0];
                acc[nt] = __builtin_amdgcn_mfma_f32_16x16x32_bf16(afrag, bfrag, acc[nt], 0, 0, 0);
            }
        }
    }
    const int node = node0 + wv * 16 + quad * 4;
    #pragma unroll
    for (int nt = 0; nt < 8; nt++) {
        const int o = nt * 16 + lcol;
        const float bias = t2b[o];
        #pragma unroll
        for (int reg = 0; reg < 4; reg++)
            out[(node + reg) * 128 + o] = acc[nt][reg] + bias;
    }
}

extern "C" void kernel_launch(void* const* d_in, const int* in_sizes, int n_in,
                              void* d_out, int out_size, void* d_ws, size_t ws_size,
                              hipStream_t stream)
{
    const float* h    = (const float*)d_in[0];
    const int*   src  = (const int*)d_in[1];
    const int*   dst  = (const int*)d_in[2];
    const float* tpw1 = (const float*)d_in[3];
    const float* tpb1 = (const float*)d_in[4];
    const float* tpa  = (const float*)d_in[5];
    const float* tpw2 = (const float*)d_in[6];
    const float* tpb2 = (const float*)d_in[7];
    const float* tmw1 = (const float*)d_in[8];
    const float* tmb1 = (const float*)d_in[9];
    const float* tma  = (const float*)d_in[10];
    const float* tmw2 = (const float*)d_in[11];
    const float* tmb2 = (const float*)d_in[12];
    const float* lng  = (const float*)d_in[13];
    const float* lnb  = (const float*)d_in[14];
    const float* bng  = (const float*)d_in[15];
    const float* bnb  = (const float*)d_in[16];
    const float* bnrm = (const float*)d_in[17];
    const float* bnrv = (const float*)d_in[18];
    const float* acta = (const float*)d_in[19];
    const float* gW1  = (const float*)d_in[20];
    const float* gb1  = (const float*)d_in[21];
    const float* ga   = (const float*)d_in[22];
    const float* gW2  = (const float*)d_in[23];
    const float* gb2  = (const float*)d_in[24];
    const float* t2w  = (const float*)d_in[25];
    const float* t2b  = (const float*)d_in[26];

    float* ws = (float*)d_ws;
    float* x0 = ws;                         // N*96
    float* x1 = x0 + N_NODES * 96;          // N*96
    float* x2 = x1 + N_NODES * 96;          // N*96
    float* eb = x2 + N_NODES * 96;          // E
    int* cnt  = (int*)(eb + N_EDGES);       // N
    int* off  = cnt + N_NODES;              // N+1
    int* cur  = off + N_NODES + 1;          // N
    int* perm = cur + N_NODES;              // E

    float* out = (float*)d_out;             // N*128 fp32
    float* ee  = out + N_NODES * 128;       // 2E fp32

    // ---- CSR build (depends only on dst; reused by both layers) ----
    hipMemsetAsync(cnt, 0, N_NODES * sizeof(int), stream);
    count_kernel<<<N_EDGES / 256, 256, 0, stream>>>(dst, cnt);
    scan_kernel<<<1, 1024, 0, stream>>>(cnt, off, cur);
    scatter_kernel<<<N_EDGES / 256, 256, 0, stream>>>(dst, cur, perm);

    // ---- fused transform (t1+t2) ----
    transform_mfma<<<dim3(200, 2), 256, 0, stream>>>(
        h, tpw1, tpb1, tpa, tpw2, tpb2, tmw1, tmb1, tma, tmw2, tmb2, x0);

    // ---- layer 0 ----
    gate_kernel<false><<<1600, 256, 0, stream>>>(x0, src, dst, gW1, gb1, ga, gW2, gb2, 0, 0, eb, nullptr);
    agg_norm_kernel<<<N_NODES, 128, 0, stream>>>(x0, src, eb, off, perm, x0,
        lng, lnb, bng, bnb, bnrm, bnrv, acta, 0, x1);

    // ---- fused: es[layer0](x1) -> ee   AND   agg-gate[layer1](x1) -> eb ----
    gate_kernel<true><<<1600, 256, 0, stream>>>(x1, src, dst, gW1, gb1, ga, gW2, gb2, 0, 1, ee, eb);

    // ---- layer 1 ----
    agg_norm_kernel<<<N_NODES, 128, 0, stream>>>(x1, src, eb, off, perm, x1,
        lng, lnb, bng, bnb, bnrm, bnrv, acta, 1, x2);
    gate_kernel<false><<<1600, 256, 0, stream>>>(x2, src, dst, gW1, gb1, ga, gW2, gb2, 1, 0, ee + N_EDGES, nullptr);

    // ---- readout ----
    final_mfma<<<N_NODES / 64, 256, 0, stream>>>(x0, x1, x2, t2w, t2b, out);
}